// Round 1
// baseline (503.532 us; speedup 1.0000x reference)
//
#include <hip/hip_runtime.h>

#define NB_ 16   // batch
#define S_ 512
#define D_ 768
#define H_ 12
#define DH_ 64

typedef __attribute__((ext_vector_type(8))) short bf16x8;
typedef __attribute__((ext_vector_type(4))) float f32x4;
typedef unsigned short ushort_t;

__device__ __forceinline__ unsigned short f2bf(float f){
  unsigned int u = __float_as_uint(f);
  u += 0x7fffu + ((u >> 16) & 1u);   // round-to-nearest-even
  return (unsigned short)(u >> 16);
}
__device__ __forceinline__ float bf2f(unsigned short s){
  return __uint_as_float(((unsigned int)s) << 16);
}

// ---------------- fp32 -> bf16 bulk convert (vectorized) ----------------
__global__ __launch_bounds__(256) void k_f32_to_bf16(const float* __restrict__ in,
                                                     ushort_t* __restrict__ out, int n4){
  int i = blockIdx.x * 256 + threadIdx.x;
  if (i < n4){
    float4 f = ((const float4*)in)[i];
    unsigned int lo = (unsigned int)f2bf(f.x) | ((unsigned int)f2bf(f.y) << 16);
    unsigned int hi = (unsigned int)f2bf(f.z) | ((unsigned int)f2bf(f.w) << 16);
    ((uint2*)out)[i] = make_uint2(lo, hi);
  }
}

// ---------------- weight transpose fp32[K][N] -> bf16[N][K] ----------------
__global__ __launch_bounds__(256) void k_wtrans(const float* __restrict__ W0, const float* __restrict__ W1,
                                                const float* __restrict__ W2, const float* __restrict__ W3,
                                                ushort_t* __restrict__ dst){
  const float* W = (blockIdx.z == 0) ? W0 : (blockIdx.z == 1) ? W1 : (blockIdx.z == 2) ? W2 : W3;
  ushort_t* o = dst + (size_t)blockIdx.z * D_ * D_;
  __shared__ float t[32][33];
  int j = threadIdx.x & 31, i0 = threadIdx.x >> 5;
  int kb = blockIdx.y * 32, nb = blockIdx.x * 32;
#pragma unroll
  for (int r = 0; r < 4; r++){
    int i = i0 + r * 8;
    t[i][j] = W[(size_t)(kb + i) * D_ + nb + j];
  }
  __syncthreads();
#pragma unroll
  for (int r = 0; r < 4; r++){
    int i = i0 + r * 8;
    o[(size_t)(nb + i) * D_ + kb + j] = f2bf(t[j][i]);
  }
}

// ---------------- pooled gate ----------------
__global__ __launch_bounds__(256) void k_pool_gate(const float* __restrict__ hs, const float* __restrict__ mask,
                                                   const float* __restrict__ Wg, const float* __restrict__ bg,
                                                   float* __restrict__ gate){
  int b = blockIdx.x, tid = threadIdx.x;
  __shared__ float red[256];
  __shared__ float hp[768];
  const float* mrow = mask + b * S_;
  float cnt = 0.f;
  for (int s = tid; s < S_; s += 256) cnt += (mrow[s] == 0.0f) ? 1.0f : 0.0f;
  red[tid] = cnt; __syncthreads();
  for (int o = 128; o > 0; o >>= 1){ if (tid < o) red[tid] += red[tid + o]; __syncthreads(); }
  float denom = fmaxf(red[0], 1.0f);
  __syncthreads();
  float a0 = 0.f, a1 = 0.f, a2 = 0.f;
  const float* base = hs + (size_t)b * S_ * D_;
  for (int s = 0; s < S_; s++){
    if (mrow[s] == 0.0f){
      const float* r = base + (size_t)s * D_;
      a0 += r[tid]; a1 += r[tid + 256]; a2 += r[tid + 512];
    }
  }
  float inv = 1.0f / denom;
  hp[tid] = a0 * inv; hp[tid + 256] = a1 * inv; hp[tid + 512] = a2 * inv;
  __syncthreads();
  float p0 = 0.f, p1 = 0.f;
  for (int d = tid; d < D_; d += 256){ p0 += hp[d] * Wg[d * 2]; p1 += hp[d] * Wg[d * 2 + 1]; }
  red[tid] = p0; __syncthreads();
  for (int o = 128; o > 0; o >>= 1){ if (tid < o) red[tid] += red[tid + o]; __syncthreads(); }
  float z0 = red[0]; __syncthreads();
  red[tid] = p1; __syncthreads();
  for (int o = 128; o > 0; o >>= 1){ if (tid < o) red[tid] += red[tid + o]; __syncthreads(); }
  float z1 = red[0];
  if (tid == 0){
    z0 = (z0 + bg[0]) * 0.5f; z1 = (z1 + bg[1]) * 0.5f;
    float m = fmaxf(z0, z1);
    float e0 = __expf(z0 - m), e1 = __expf(z1 - m);
    float ssum = e0 + e1;
    gate[b * 2] = e0 / ssum; gate[b * 2 + 1] = e1 / ssum;
  }
}

// ---------------- generic BT GEMM: C[z] = act(alpha*A[z]*B[z]^T + bias) ----------------
// A: [M][K] row-major bf16 (lda), B: [N][K] row-major bf16 (ldb). Batch offset split as
// z = zb*H + zh with separate strides so strided head-slices work.
template<int BN, int OUTBF16, int RELU, int RESID>
__global__ __launch_bounds__(256) void k_gemm_bt(
    const ushort_t* __restrict__ A, long sAb, long sAh, int lda,
    const ushort_t* __restrict__ Bm, long sBb, long sBh, int ldb,
    void* __restrict__ Cp, long sCb, long sCh, int ldc,
    const float* __restrict__ bias, long biasStride,
    const float* __restrict__ resid, float alpha, int K)
{
  __shared__ ushort_t As[128 * 32];
  __shared__ ushort_t Bs[BN * 32];
  const int z = blockIdx.z;
  const int zb = z / H_, zh = z - zb * H_;
  const ushort_t* Ab = A + zb * sAb + zh * sAh;
  const ushort_t* Bb = Bm + zb * sBb + zh * sBh;
  const long coff = zb * sCb + zh * sCh;
  const int tid = threadIdx.x;
  const int m0 = blockIdx.y * 128, n0 = blockIdx.x * BN;
  const int wid = tid >> 6, lane = tid & 63;
  const int quad = lane >> 4, l16 = lane & 15;
  constexpr int MI = (BN == 128) ? 4 : 2;
  const int wm = (BN == 128) ? (wid >> 1) : wid;
  const int wn = (BN == 128) ? (wid & 1) : 0;

  f32x4 acc[MI][4];
#pragma unroll
  for (int i = 0; i < MI; i++)
#pragma unroll
    for (int j = 0; j < 4; j++) acc[i][j] = (f32x4){0.f, 0.f, 0.f, 0.f};

  for (int k0 = 0; k0 < K; k0 += 32){
#pragma unroll
    for (int c = 0; c < 2; c++){
      int chunk = tid + c * 256;          // 512 chunks of 8 bf16 for A tile
      int row = chunk >> 2, off = (chunk & 3) * 8;
      *(float4*)(&As[row * 32 + off]) = *(const float4*)(Ab + (size_t)(m0 + row) * lda + k0 + off);
    }
#pragma unroll
    for (int c = 0; c < (BN * 4) / 256; c++){
      int chunk = tid + c * 256;
      int row = chunk >> 2, off = (chunk & 3) * 8;
      *(float4*)(&Bs[row * 32 + off]) = *(const float4*)(Bb + (size_t)(n0 + row) * ldb + k0 + off);
    }
    __syncthreads();
    bf16x8 af[MI], bfv[4];
#pragma unroll
    for (int mi = 0; mi < MI; mi++)
      af[mi] = *(const bf16x8*)(&As[(wm * (MI * 16) + mi * 16 + l16) * 32 + quad * 8]);
#pragma unroll
    for (int ni = 0; ni < 4; ni++)
      bfv[ni] = *(const bf16x8*)(&Bs[(wn * 64 + ni * 16 + l16) * 32 + quad * 8]);
#pragma unroll
    for (int mi = 0; mi < MI; mi++)
#pragma unroll
      for (int ni = 0; ni < 4; ni++)
        acc[mi][ni] = __builtin_amdgcn_mfma_f32_16x16x32_bf16(af[mi], bfv[ni], acc[mi][ni], 0, 0, 0);
    __syncthreads();
  }

  const float* bv = bias ? (bias + zb * biasStride) : nullptr;
#pragma unroll
  for (int mi = 0; mi < MI; mi++){
#pragma unroll
    for (int ni = 0; ni < 4; ni++){
      int col = n0 + wn * 64 + ni * 16 + l16;
      float bcol = bv ? bv[col] : 0.0f;
#pragma unroll
      for (int r = 0; r < 4; r++){
        int row = m0 + wm * (MI * 16) + mi * 16 + quad * 4 + r;
        float v = acc[mi][ni][r] * alpha + bcol;
        if (RELU) v = fmaxf(v, 0.0f);
        if (RESID) v += resid[(size_t)row * ldc + col];
        long idx = coff + (long)row * ldc + col;
        if (OUTBF16) ((ushort_t*)Cp)[idx] = f2bf(v);
        else         ((float*)Cp)[idx] = v;
      }
    }
  }
}

// ---------------- per-head V transpose: vt[b,h,d,s] = v[b,s,h*64+d] ----------------
__global__ __launch_bounds__(256) void k_vtrans(const ushort_t* __restrict__ v, ushort_t* __restrict__ vt){
  __shared__ ushort_t t[64][66];
  int st = blockIdx.x * 64; int z = blockIdx.y;
  int b = z / H_, h = z - b * H_;
  int tid = threadIdx.x;
  const ushort_t* src = v + (size_t)b * S_ * D_ + (size_t)st * D_ + h * DH_;
#pragma unroll
  for (int rep = 0; rep < 8; rep++){
    int idx = rep * 256 + tid;
    int i = idx >> 5, u = idx & 31;
    unsigned int val = *(const unsigned int*)(src + (size_t)i * D_ + u * 2);
    *(unsigned int*)(&t[i][u * 2]) = val;
  }
  __syncthreads();
  ushort_t* dst = vt + (size_t)z * DH_ * S_ + st;
#pragma unroll
  for (int rep = 0; rep < 8; rep++){
    int idx = rep * 256 + tid;
    int d = idx >> 5, u2 = idx & 31;
    unsigned int val = (unsigned int)t[u2 * 2][d] | ((unsigned int)t[u2 * 2 + 1][d] << 16);
    *(unsigned int*)(dst + (size_t)d * S_ + u2 * 2) = val;
  }
}

// ---------------- no-max softmax + gate-mix with prior (in-place on bf16 scores) ----------------
__global__ __launch_bounds__(256) void k_softmax(ushort_t* __restrict__ probs, const float* __restrict__ prior,
                                                 const float* __restrict__ gate){
  int gid = blockIdx.x * 4 + (threadIdx.x >> 6);   // row over B*H*S
  int lane = threadIdx.x & 63;
  int s = gid & (S_ - 1);
  int bh = gid >> 9;
  int b = bh / H_;
  ushort_t* row = probs + (size_t)gid * S_;
  uint4 u = *(uint4*)(row + lane * 8);
  unsigned int uw[4] = {u.x, u.y, u.z, u.w};
  float e[8]; float l = 0.f;
#pragma unroll
  for (int w2 = 0; w2 < 4; w2++){
    float lo = bf2f((unsigned short)(uw[w2] & 0xffffu));
    float hi = bf2f((unsigned short)(uw[w2] >> 16));
    e[w2 * 2] = __expf(lo); e[w2 * 2 + 1] = __expf(hi);
    l += e[w2 * 2] + e[w2 * 2 + 1];
  }
#pragma unroll
  for (int o = 32; o > 0; o >>= 1) l += __shfl_down(l, o);
  l = __shfl(l, 0);
  float g0 = gate[b * 2], g1 = gate[b * 2 + 1];
  float scale = g0 / l;
  const float* pr = prior + ((size_t)(b * S_ + s)) * S_ + lane * 8;
  float4 pa = *(const float4*)(pr);
  float4 pb = *(const float4*)(pr + 4);
  float pv[8] = {pa.x, pa.y, pa.z, pa.w, pb.x, pb.y, pb.z, pb.w};
  unsigned int ow[4];
#pragma unroll
  for (int w2 = 0; w2 < 4; w2++){
    unsigned short lo = f2bf(e[w2 * 2] * scale + pv[w2 * 2] * g1);
    unsigned short hi = f2bf(e[w2 * 2 + 1] * scale + pv[w2 * 2 + 1] * g1);
    ow[w2] = (unsigned int)lo | ((unsigned int)hi << 16);
  }
  *(uint4*)(row + lane * 8) = make_uint4(ow[0], ow[1], ow[2], ow[3]);
}

// ---------------- in-place LayerNorm over D=768 ----------------
__global__ __launch_bounds__(256) void k_ln(float* __restrict__ out, const float* __restrict__ gamma,
                                            const float* __restrict__ beta){
  __shared__ float red[256];
  int row = blockIdx.x, tid = threadIdx.x;
  float* p = out + (size_t)row * D_;
  float x0 = p[tid], x1 = p[tid + 256], x2 = p[tid + 512];
  red[tid] = x0 + x1 + x2; __syncthreads();
  for (int o = 128; o > 0; o >>= 1){ if (tid < o) red[tid] += red[tid + o]; __syncthreads(); }
  float mu = red[0] * (1.0f / 768.0f);
  __syncthreads();
  float d0 = x0 - mu, d1 = x1 - mu, d2 = x2 - mu;
  red[tid] = d0 * d0 + d1 * d1 + d2 * d2; __syncthreads();
  for (int o = 128; o > 0; o >>= 1){ if (tid < o) red[tid] += red[tid + o]; __syncthreads(); }
  float rs = rsqrtf(red[0] * (1.0f / 768.0f) + 1e-5f);
  p[tid]       = d0 * rs * gamma[tid]       + beta[tid];
  p[tid + 256] = d1 * rs * gamma[tid + 256] + beta[tid + 256];
  p[tid + 512] = d2 * rs * gamma[tid + 512] + beta[tid + 512];
}

extern "C" void kernel_launch(void* const* d_in, const int* in_sizes, int n_in,
                              void* d_out, int out_size, void* d_ws, size_t ws_size,
                              hipStream_t stream){
  const float* hs    = (const float*)d_in[0];
  const float* mask  = (const float*)d_in[1];
  const float* prior = (const float*)d_in[2];
  const float* Wq = (const float*)d_in[3];  const float* bq = (const float*)d_in[4];
  const float* Wk = (const float*)d_in[5];  const float* bk = (const float*)d_in[6];
  const float* Wv = (const float*)d_in[7];  const float* bv = (const float*)d_in[8];
  const float* Wg = (const float*)d_in[9];  const float* bg = (const float*)d_in[10];
  const float* Wo = (const float*)d_in[11]; const float* bo = (const float*)d_in[12];
  const float* gamma = (const float*)d_in[13]; const float* beta = (const float*)d_in[14];
  float* out = (float*)d_out;

  size_t off = 0;
  auto alloc = [&](size_t bytes) -> char* {
    char* p = (char*)d_ws + off;
    off += (bytes + 255) & ~(size_t)255;
    return p;
  };
  const size_t HSD = (size_t)NB_ * S_ * D_;          // 6.29M elems
  ushort_t* hsb   = (ushort_t*)alloc(HSD * 2);
  ushort_t* qb    = (ushort_t*)alloc(HSD * 2);
  ushort_t* kb    = (ushort_t*)alloc(HSD * 2);
  ushort_t* vb    = (ushort_t*)alloc(HSD * 2);
  ushort_t* vtb   = (ushort_t*)alloc(HSD * 2);
  ushort_t* wt    = (ushort_t*)alloc((size_t)4 * D_ * D_ * 2);
  ushort_t* probs = (ushort_t*)alloc((size_t)NB_ * H_ * S_ * S_ * 2);
  ushort_t* ctx   = (ushort_t*)alloc(HSD * 2);
  float*    gate  = (float*)alloc(256);

  // 1. converts
  k_f32_to_bf16<<<dim3((int)(HSD / 4 / 256)), 256, 0, stream>>>(hs, hsb, (int)(HSD / 4));
  k_wtrans<<<dim3(24, 24, 4), 256, 0, stream>>>(Wq, Wk, Wv, Wo, wt);
  // 2. gate
  k_pool_gate<<<dim3(NB_), 256, 0, stream>>>(hs, mask, Wg, bg, gate);
  // 3. QKV projections (bf16 out)
  k_gemm_bt<128, 1, 0, 0><<<dim3(6, 64, 1), 256, 0, stream>>>(
      hsb, 0, 0, D_, wt + 0 * (size_t)D_ * D_, 0, 0, D_, qb, 0, 0, D_, bq, 0, nullptr, 1.0f, D_);
  k_gemm_bt<128, 1, 0, 0><<<dim3(6, 64, 1), 256, 0, stream>>>(
      hsb, 0, 0, D_, wt + 1 * (size_t)D_ * D_, 0, 0, D_, kb, 0, 0, D_, bk, 0, nullptr, 1.0f, D_);
  k_gemm_bt<128, 1, 0, 0><<<dim3(6, 64, 1), 256, 0, stream>>>(
      hsb, 0, 0, D_, wt + 2 * (size_t)D_ * D_, 0, 0, D_, vb, 0, 0, D_, bv, 0, nullptr, 1.0f, D_);
  // 4. scores = 0.125*Q·K^T + mask  (batched over B*H, bf16 out)
  k_gemm_bt<128, 1, 0, 0><<<dim3(4, 4, NB_ * H_), 256, 0, stream>>>(
      qb, (long)S_ * D_, 64, D_, kb, (long)S_ * D_, 64, D_,
      probs, (long)H_ * S_ * S_, (long)S_ * S_, S_, mask, S_, nullptr, 0.125f, DH_);
  // 5. softmax + gate mix with prior (in place)
  k_softmax<<<dim3(NB_ * H_ * S_ / 4), 256, 0, stream>>>(probs, prior, gate);
  // 6. V transpose per head
  k_vtrans<<<dim3(S_ / 64, NB_ * H_), 256, 0, stream>>>(vb, vtb);
  // 7. ctx = probs·V  (batched, bf16 out into [B,S,D] head slices)
  k_gemm_bt<64, 1, 0, 0><<<dim3(1, 4, NB_ * H_), 256, 0, stream>>>(
      probs, (long)H_ * S_ * S_, (long)S_ * S_, S_, vtb, (long)H_ * DH_ * S_, (long)DH_ * S_, S_,
      ctx, (long)S_ * D_, 64, D_, nullptr, 0, nullptr, 1.0f, S_);
  // 8. out = relu(ctx·Wo + bo) + hs  (fp32 into d_out)
  k_gemm_bt<128, 0, 1, 1><<<dim3(6, 64, 1), 256, 0, stream>>>(
      ctx, 0, 0, D_, wt + 3 * (size_t)D_ * D_, 0, 0, D_, out, 0, 0, D_, bo, 0, hs, 1.0f, D_);
  // 9. LayerNorm in place on d_out
  k_ln<<<dim3(NB_ * S_), 256, 0, stream>>>(out, gamma, beta);
}

// Round 2
// 389.320 us; speedup vs baseline: 1.2934x; 1.2934x over previous
//
#include <hip/hip_runtime.h>

#define NB_ 16   // batch
#define S_ 512
#define D_ 768
#define H_ 12
#define DH_ 64

typedef __attribute__((ext_vector_type(8))) short bf16x8;
typedef __attribute__((ext_vector_type(4))) float f32x4;
typedef unsigned short ushort_t;

__device__ __forceinline__ unsigned short f2bf(float f){
  unsigned int u = __float_as_uint(f);
  u += 0x7fffu + ((u >> 16) & 1u);   // round-to-nearest-even
  return (unsigned short)(u >> 16);
}
__device__ __forceinline__ float bf2f(unsigned short s){
  return __uint_as_float(((unsigned int)s) << 16);
}

// ---------------- fp32 -> bf16 bulk convert (vectorized) ----------------
__global__ __launch_bounds__(256) void k_f32_to_bf16(const float* __restrict__ in,
                                                     ushort_t* __restrict__ out, int n4){
  int i = blockIdx.x * 256 + threadIdx.x;
  if (i < n4){
    float4 f = ((const float4*)in)[i];
    unsigned int lo = (unsigned int)f2bf(f.x) | ((unsigned int)f2bf(f.y) << 16);
    unsigned int hi = (unsigned int)f2bf(f.z) | ((unsigned int)f2bf(f.w) << 16);
    ((uint2*)out)[i] = make_uint2(lo, hi);
  }
}

// ---------------- weight transpose fp32[K][N] -> bf16[N][K] ----------------
__global__ __launch_bounds__(256) void k_wtrans(const float* __restrict__ W0, const float* __restrict__ W1,
                                                const float* __restrict__ W2, const float* __restrict__ W3,
                                                ushort_t* __restrict__ dst){
  const float* W = (blockIdx.z == 0) ? W0 : (blockIdx.z == 1) ? W1 : (blockIdx.z == 2) ? W2 : W3;
  ushort_t* o = dst + (size_t)blockIdx.z * D_ * D_;
  __shared__ float t[32][33];
  int j = threadIdx.x & 31, i0 = threadIdx.x >> 5;
  int kb = blockIdx.y * 32, nb = blockIdx.x * 32;
#pragma unroll
  for (int r = 0; r < 4; r++){
    int i = i0 + r * 8;
    t[i][j] = W[(size_t)(kb + i) * D_ + nb + j];
  }
  __syncthreads();
#pragma unroll
  for (int r = 0; r < 4; r++){
    int i = i0 + r * 8;
    o[(size_t)(nb + i) * D_ + kb + j] = f2bf(t[j][i]);
  }
}

// ---------------- pooled gate, stage 1: partial sums over 64-row chunks ----------------
// grid (8, B): partial[(b*8+chunk)*768 + d], pcnt[b*8+chunk]
__global__ __launch_bounds__(256) void k_pool1(const float* __restrict__ hs, const float* __restrict__ mask,
                                               float* __restrict__ partial, float* __restrict__ pcnt){
  int chunk = blockIdx.x, b = blockIdx.y, tid = threadIdx.x;
  const float* mrow = mask + b * S_ + chunk * 64;
  const float* base = hs + ((size_t)b * S_ + chunk * 64) * D_;
  float a0 = 0.f, a1 = 0.f, a2 = 0.f, cnt = 0.f;
#pragma unroll 4
  for (int s = 0; s < 64; s++){
    if (mrow[s] == 0.0f){
      const float* r = base + (size_t)s * D_;
      a0 += r[tid]; a1 += r[tid + 256]; a2 += r[tid + 512];
      cnt += 1.0f;
    }
  }
  float* o = partial + (size_t)(b * 8 + chunk) * D_;
  o[tid] = a0; o[tid + 256] = a1; o[tid + 512] = a2;
  if (tid == 0) pcnt[b * 8 + chunk] = cnt;
}

// ---------------- pooled gate, stage 2: reduce partials, linear, softmax ----------------
__global__ __launch_bounds__(256) void k_pool2(const float* __restrict__ partial, const float* __restrict__ pcnt,
                                               const float* __restrict__ Wg, const float* __restrict__ bg,
                                               float* __restrict__ gate){
  int b = blockIdx.x, tid = threadIdx.x;
  __shared__ float red[256];
  __shared__ float hp[768];
  float a0 = 0.f, a1 = 0.f, a2 = 0.f;
#pragma unroll
  for (int c = 0; c < 8; c++){
    const float* p = partial + (size_t)(b * 8 + c) * D_;
    a0 += p[tid]; a1 += p[tid + 256]; a2 += p[tid + 512];
  }
  float denom = 0.f;
#pragma unroll
  for (int c = 0; c < 8; c++) denom += pcnt[b * 8 + c];
  float inv = 1.0f / fmaxf(denom, 1.0f);
  hp[tid] = a0 * inv; hp[tid + 256] = a1 * inv; hp[tid + 512] = a2 * inv;
  __syncthreads();
  float p0 = 0.f, p1 = 0.f;
  for (int d = tid; d < D_; d += 256){ p0 += hp[d] * Wg[d * 2]; p1 += hp[d] * Wg[d * 2 + 1]; }
  red[tid] = p0; __syncthreads();
  for (int o = 128; o > 0; o >>= 1){ if (tid < o) red[tid] += red[tid + o]; __syncthreads(); }
  float z0 = red[0]; __syncthreads();
  red[tid] = p1; __syncthreads();
  for (int o = 128; o > 0; o >>= 1){ if (tid < o) red[tid] += red[tid + o]; __syncthreads(); }
  float z1 = red[0];
  if (tid == 0){
    z0 = (z0 + bg[0]) * 0.5f; z1 = (z1 + bg[1]) * 0.5f;
    float m = fmaxf(z0, z1);
    float e0 = __expf(z0 - m), e1 = __expf(z1 - m);
    float ssum = e0 + e1;
    gate[b * 2] = e0 / ssum; gate[b * 2 + 1] = e1 / ssum;
  }
}

// ---------------- generic BT GEMM: C[z] = act(alpha*A[z]*B[z]^T + bias) ----------------
// A: [M][K] row-major bf16 (lda), B: [N][K] row-major bf16 (ldb). Batch offset split as
// z = zb*H + zh with separate strides so strided head-slices work.
template<int BN, int OUTBF16, int RELU, int RESID>
__global__ __launch_bounds__(256) void k_gemm_bt(
    const ushort_t* __restrict__ A, long sAb, long sAh, int lda,
    const ushort_t* __restrict__ Bm, long sBb, long sBh, int ldb,
    void* __restrict__ Cp, long sCb, long sCh, int ldc,
    const float* __restrict__ bias, long biasStride,
    const float* __restrict__ resid, float alpha, int K)
{
  __shared__ ushort_t As[128 * 32];
  __shared__ ushort_t Bs[BN * 32];
  const int z = blockIdx.z;
  const int zb = z / H_, zh = z - zb * H_;
  const ushort_t* Ab = A + zb * sAb + zh * sAh;
  const ushort_t* Bb = Bm + zb * sBb + zh * sBh;
  const long coff = zb * sCb + zh * sCh;
  const int tid = threadIdx.x;
  const int m0 = blockIdx.y * 128, n0 = blockIdx.x * BN;
  const int wid = tid >> 6, lane = tid & 63;
  const int quad = lane >> 4, l16 = lane & 15;
  constexpr int MI = (BN == 128) ? 4 : 2;
  const int wm = (BN == 128) ? (wid >> 1) : wid;
  const int wn = (BN == 128) ? (wid & 1) : 0;

  f32x4 acc[MI][4];
#pragma unroll
  for (int i = 0; i < MI; i++)
#pragma unroll
    for (int j = 0; j < 4; j++) acc[i][j] = (f32x4){0.f, 0.f, 0.f, 0.f};

  for (int k0 = 0; k0 < K; k0 += 32){
#pragma unroll
    for (int c = 0; c < 2; c++){
      int chunk = tid + c * 256;          // 512 chunks of 8 bf16 for A tile
      int row = chunk >> 2, off = (chunk & 3) * 8;
      *(float4*)(&As[row * 32 + off]) = *(const float4*)(Ab + (size_t)(m0 + row) * lda + k0 + off);
    }
#pragma unroll
    for (int c = 0; c < (BN * 4) / 256; c++){
      int chunk = tid + c * 256;
      int row = chunk >> 2, off = (chunk & 3) * 8;
      *(float4*)(&Bs[row * 32 + off]) = *(const float4*)(Bb + (size_t)(n0 + row) * ldb + k0 + off);
    }
    __syncthreads();
    bf16x8 af[MI], bfv[4];
#pragma unroll
    for (int mi = 0; mi < MI; mi++)
      af[mi] = *(const bf16x8*)(&As[(wm * (MI * 16) + mi * 16 + l16) * 32 + quad * 8]);
#pragma unroll
    for (int ni = 0; ni < 4; ni++)
      bfv[ni] = *(const bf16x8*)(&Bs[(wn * 64 + ni * 16 + l16) * 32 + quad * 8]);
#pragma unroll
    for (int mi = 0; mi < MI; mi++)
#pragma unroll
      for (int ni = 0; ni < 4; ni++)
        acc[mi][ni] = __builtin_amdgcn_mfma_f32_16x16x32_bf16(af[mi], bfv[ni], acc[mi][ni], 0, 0, 0);
    __syncthreads();
  }

  const float* bv = bias ? (bias + zb * biasStride) : nullptr;
#pragma unroll
  for (int mi = 0; mi < MI; mi++){
#pragma unroll
    for (int ni = 0; ni < 4; ni++){
      int col = n0 + wn * 64 + ni * 16 + l16;
      float bcol = bv ? bv[col] : 0.0f;
#pragma unroll
      for (int r = 0; r < 4; r++){
        int row = m0 + wm * (MI * 16) + mi * 16 + quad * 4 + r;
        float v = acc[mi][ni][r] * alpha + bcol;
        if (RELU) v = fmaxf(v, 0.0f);
        if (RESID) v += resid[(size_t)row * ldc + col];
        long idx = coff + (long)row * ldc + col;
        if (OUTBF16) ((ushort_t*)Cp)[idx] = f2bf(v);
        else         ((float*)Cp)[idx] = v;
      }
    }
  }
}

// ---------------- per-head V transpose: vt[b,h,d,s] = v[b,s,h*64+d] ----------------
__global__ __launch_bounds__(256) void k_vtrans(const ushort_t* __restrict__ v, ushort_t* __restrict__ vt){
  __shared__ ushort_t t[64][66];
  int st = blockIdx.x * 64; int z = blockIdx.y;
  int b = z / H_, h = z - b * H_;
  int tid = threadIdx.x;
  const ushort_t* src = v + (size_t)b * S_ * D_ + (size_t)st * D_ + h * DH_;
#pragma unroll
  for (int rep = 0; rep < 8; rep++){
    int idx = rep * 256 + tid;
    int i = idx >> 5, u = idx & 31;
    unsigned int val = *(const unsigned int*)(src + (size_t)i * D_ + u * 2);
    *(unsigned int*)(&t[i][u * 2]) = val;
  }
  __syncthreads();
  ushort_t* dst = vt + (size_t)z * DH_ * S_ + st;
#pragma unroll
  for (int rep = 0; rep < 8; rep++){
    int idx = rep * 256 + tid;
    int d = idx >> 5, u2 = idx & 31;
    unsigned int val = (unsigned int)t[u2 * 2][d] | ((unsigned int)t[u2 * 2 + 1][d] << 16);
    *(unsigned int*)(dst + (size_t)d * S_ + u2 * 2) = val;
  }
}

// ---------------- no-max softmax + gate-mix with prior (in-place on bf16 scores) ----------------
__global__ __launch_bounds__(256) void k_softmax(ushort_t* __restrict__ probs, const float* __restrict__ prior,
                                                 const float* __restrict__ gate){
  int gid = blockIdx.x * 4 + (threadIdx.x >> 6);   // row over B*H*S
  int lane = threadIdx.x & 63;
  int s = gid & (S_ - 1);
  int bh = gid >> 9;
  int b = bh / H_;
  ushort_t* row = probs + (size_t)gid * S_;
  uint4 u = *(uint4*)(row + lane * 8);
  unsigned int uw[4] = {u.x, u.y, u.z, u.w};
  float e[8]; float l = 0.f;
#pragma unroll
  for (int w2 = 0; w2 < 4; w2++){
    float lo = bf2f((unsigned short)(uw[w2] & 0xffffu));
    float hi = bf2f((unsigned short)(uw[w2] >> 16));
    e[w2 * 2] = __expf(lo); e[w2 * 2 + 1] = __expf(hi);
    l += e[w2 * 2] + e[w2 * 2 + 1];
  }
#pragma unroll
  for (int o = 32; o > 0; o >>= 1) l += __shfl_down(l, o);
  l = __shfl(l, 0);
  float g0 = gate[b * 2], g1 = gate[b * 2 + 1];
  float scale = g0 / l;
  const float* pr = prior + ((size_t)(b * S_ + s)) * S_ + lane * 8;
  float4 pa = *(const float4*)(pr);
  float4 pb = *(const float4*)(pr + 4);
  float pv[8] = {pa.x, pa.y, pa.z, pa.w, pb.x, pb.y, pb.z, pb.w};
  unsigned int ow[4];
#pragma unroll
  for (int w2 = 0; w2 < 4; w2++){
    unsigned short lo = f2bf(e[w2 * 2] * scale + pv[w2 * 2] * g1);
    unsigned short hi = f2bf(e[w2 * 2 + 1] * scale + pv[w2 * 2 + 1] * g1);
    ow[w2] = (unsigned int)lo | ((unsigned int)hi << 16);
  }
  *(uint4*)(row + lane * 8) = make_uint4(ow[0], ow[1], ow[2], ow[3]);
}

// ---------------- in-place LayerNorm over D=768 ----------------
__global__ __launch_bounds__(256) void k_ln(float* __restrict__ out, const float* __restrict__ gamma,
                                            const float* __restrict__ beta){
  __shared__ float red[256];
  int row = blockIdx.x, tid = threadIdx.x;
  float* p = out + (size_t)row * D_;
  float x0 = p[tid], x1 = p[tid + 256], x2 = p[tid + 512];
  red[tid] = x0 + x1 + x2; __syncthreads();
  for (int o = 128; o > 0; o >>= 1){ if (tid < o) red[tid] += red[tid + o]; __syncthreads(); }
  float mu = red[0] * (1.0f / 768.0f);
  __syncthreads();
  float d0 = x0 - mu, d1 = x1 - mu, d2 = x2 - mu;
  red[tid] = d0 * d0 + d1 * d1 + d2 * d2; __syncthreads();
  for (int o = 128; o > 0; o >>= 1){ if (tid < o) red[tid] += red[tid + o]; __syncthreads(); }
  float rs = rsqrtf(red[0] * (1.0f / 768.0f) + 1e-5f);
  p[tid]       = d0 * rs * gamma[tid]       + beta[tid];
  p[tid + 256] = d1 * rs * gamma[tid + 256] + beta[tid + 256];
  p[tid + 512] = d2 * rs * gamma[tid + 512] + beta[tid + 512];
}

extern "C" void kernel_launch(void* const* d_in, const int* in_sizes, int n_in,
                              void* d_out, int out_size, void* d_ws, size_t ws_size,
                              hipStream_t stream){
  const float* hs    = (const float*)d_in[0];
  const float* mask  = (const float*)d_in[1];
  const float* prior = (const float*)d_in[2];
  const float* Wq = (const float*)d_in[3];  const float* bq = (const float*)d_in[4];
  const float* Wk = (const float*)d_in[5];  const float* bk = (const float*)d_in[6];
  const float* Wv = (const float*)d_in[7];  const float* bv = (const float*)d_in[8];
  const float* Wg = (const float*)d_in[9];  const float* bg = (const float*)d_in[10];
  const float* Wo = (const float*)d_in[11]; const float* bo = (const float*)d_in[12];
  const float* gamma = (const float*)d_in[13]; const float* beta = (const float*)d_in[14];
  float* out = (float*)d_out;

  size_t off = 0;
  auto alloc = [&](size_t bytes) -> char* {
    char* p = (char*)d_ws + off;
    off += (bytes + 255) & ~(size_t)255;
    return p;
  };
  const size_t HSD = (size_t)NB_ * S_ * D_;          // 6.29M elems
  ushort_t* hsb   = (ushort_t*)alloc(HSD * 2);
  ushort_t* qb    = (ushort_t*)alloc(HSD * 2);
  ushort_t* kb    = (ushort_t*)alloc(HSD * 2);
  ushort_t* vb    = (ushort_t*)alloc(HSD * 2);
  ushort_t* vtb   = (ushort_t*)alloc(HSD * 2);
  ushort_t* wt    = (ushort_t*)alloc((size_t)4 * D_ * D_ * 2);
  ushort_t* probs = (ushort_t*)alloc((size_t)NB_ * H_ * S_ * S_ * 2);
  ushort_t* ctx   = (ushort_t*)alloc(HSD * 2);
  float*    gate  = (float*)alloc(256);
  float*    partial = (float*)alloc((size_t)NB_ * 8 * D_ * 4);
  float*    pcnt  = (float*)alloc((size_t)NB_ * 8 * 4);

  // 1. converts
  k_f32_to_bf16<<<dim3((int)(HSD / 4 / 256)), 256, 0, stream>>>(hs, hsb, (int)(HSD / 4));
  k_wtrans<<<dim3(24, 24, 4), 256, 0, stream>>>(Wq, Wk, Wv, Wo, wt);
  // 2. gate (two-stage parallel pooling)
  k_pool1<<<dim3(8, NB_), 256, 0, stream>>>(hs, mask, partial, pcnt);
  k_pool2<<<dim3(NB_), 256, 0, stream>>>(partial, pcnt, Wg, bg, gate);
  // 3. QKV projections (bf16 out)
  k_gemm_bt<128, 1, 0, 0><<<dim3(6, 64, 1), 256, 0, stream>>>(
      hsb, 0, 0, D_, wt + 0 * (size_t)D_ * D_, 0, 0, D_, qb, 0, 0, D_, bq, 0, nullptr, 1.0f, D_);
  k_gemm_bt<128, 1, 0, 0><<<dim3(6, 64, 1), 256, 0, stream>>>(
      hsb, 0, 0, D_, wt + 1 * (size_t)D_ * D_, 0, 0, D_, kb, 0, 0, D_, bk, 0, nullptr, 1.0f, D_);
  k_gemm_bt<128, 1, 0, 0><<<dim3(6, 64, 1), 256, 0, stream>>>(
      hsb, 0, 0, D_, wt + 2 * (size_t)D_ * D_, 0, 0, D_, vb, 0, 0, D_, bv, 0, nullptr, 1.0f, D_);
  // 4. scores = 0.125*Q·K^T + mask  (batched over B*H, bf16 out)
  k_gemm_bt<128, 1, 0, 0><<<dim3(4, 4, NB_ * H_), 256, 0, stream>>>(
      qb, (long)S_ * D_, 64, D_, kb, (long)S_ * D_, 64, D_,
      probs, (long)H_ * S_ * S_, (long)S_ * S_, S_, mask, S_, nullptr, 0.125f, DH_);
  // 5. softmax + gate mix with prior (in place)
  k_softmax<<<dim3(NB_ * H_ * S_ / 4), 256, 0, stream>>>(probs, prior, gate);
  // 6. V transpose per head
  k_vtrans<<<dim3(S_ / 64, NB_ * H_), 256, 0, stream>>>(vb, vtb);
  // 7. ctx = probs·V  (batched, bf16 out into [B,S,D] head slices)
  k_gemm_bt<64, 1, 0, 0><<<dim3(1, 4, NB_ * H_), 256, 0, stream>>>(
      probs, (long)H_ * S_ * S_, (long)S_ * S_, S_, vtb, (long)H_ * DH_ * S_, (long)DH_ * S_, S_,
      ctx, (long)S_ * D_, 64, D_, nullptr, 0, nullptr, 1.0f, S_);
  // 8. out = relu(ctx·Wo + bo) + hs  (fp32 into d_out)
  k_gemm_bt<128, 0, 1, 1><<<dim3(6, 64, 1), 256, 0, stream>>>(
      ctx, 0, 0, D_, wt + 3 * (size_t)D_ * D_, 0, 0, D_, out, 0, 0, D_, bo, 0, hs, 1.0f, D_);
  // 9. LayerNorm in place on d_out
  k_ln<<<dim3(NB_ * S_), 256, 0, stream>>>(out, gamma, beta);
}

// Round 3
// 362.684 us; speedup vs baseline: 1.3883x; 1.0734x over previous
//
#include <hip/hip_runtime.h>

#define NB_ 16   // batch
#define S_ 512
#define D_ 768
#define H_ 12
#define DH_ 64
#define BHS_ (NB_ * H_ * S_)   // 98304

typedef __attribute__((ext_vector_type(8))) short bf16x8;
typedef __attribute__((ext_vector_type(4))) float f32x4;
typedef unsigned short ushort_t;

__device__ __forceinline__ unsigned short f2bf(float f){
  unsigned int u = __float_as_uint(f);
  u += 0x7fffu + ((u >> 16) & 1u);   // round-to-nearest-even
  return (unsigned short)(u >> 16);
}
__device__ __forceinline__ float bf2f(unsigned short s){
  return __uint_as_float(((unsigned int)s) << 16);
}

// ---------------- fp32 -> bf16 bulk convert (vectorized) ----------------
__global__ __launch_bounds__(256) void k_f32_to_bf16(const float* __restrict__ in,
                                                     ushort_t* __restrict__ out, int n4){
  int i = blockIdx.x * 256 + threadIdx.x;
  if (i < n4){
    float4 f = ((const float4*)in)[i];
    unsigned int lo = (unsigned int)f2bf(f.x) | ((unsigned int)f2bf(f.y) << 16);
    unsigned int hi = (unsigned int)f2bf(f.z) | ((unsigned int)f2bf(f.w) << 16);
    ((uint2*)out)[i] = make_uint2(lo, hi);
  }
}

// ---------------- weight transpose fp32[K][N] -> bf16[N][K] ----------------
__global__ __launch_bounds__(256) void k_wtrans(const float* __restrict__ W0, const float* __restrict__ W1,
                                                const float* __restrict__ W2, const float* __restrict__ W3,
                                                ushort_t* __restrict__ dst){
  const float* W = (blockIdx.z == 0) ? W0 : (blockIdx.z == 1) ? W1 : (blockIdx.z == 2) ? W2 : W3;
  ushort_t* o = dst + (size_t)blockIdx.z * D_ * D_;
  __shared__ float t[32][33];
  int j = threadIdx.x & 31, i0 = threadIdx.x >> 5;
  int kb = blockIdx.y * 32, nb = blockIdx.x * 32;
#pragma unroll
  for (int r = 0; r < 4; r++){
    int i = i0 + r * 8;
    t[i][j] = W[(size_t)(kb + i) * D_ + nb + j];
  }
  __syncthreads();
#pragma unroll
  for (int r = 0; r < 4; r++){
    int i = i0 + r * 8;
    o[(size_t)(nb + i) * D_ + kb + j] = f2bf(t[j][i]);
  }
}

// ---------------- pooled gate, stage 1: partial sums over 64-row chunks ----------------
__global__ __launch_bounds__(256) void k_pool1(const float* __restrict__ hs, const float* __restrict__ mask,
                                               float* __restrict__ partial, float* __restrict__ pcnt){
  int chunk = blockIdx.x, b = blockIdx.y, tid = threadIdx.x;
  const float* mrow = mask + b * S_ + chunk * 64;
  const float* base = hs + ((size_t)b * S_ + chunk * 64) * D_;
  float a0 = 0.f, a1 = 0.f, a2 = 0.f, cnt = 0.f;
#pragma unroll 4
  for (int s = 0; s < 64; s++){
    if (mrow[s] == 0.0f){
      const float* r = base + (size_t)s * D_;
      a0 += r[tid]; a1 += r[tid + 256]; a2 += r[tid + 512];
      cnt += 1.0f;
    }
  }
  float* o = partial + (size_t)(b * 8 + chunk) * D_;
  o[tid] = a0; o[tid + 256] = a1; o[tid + 512] = a2;
  if (tid == 0) pcnt[b * 8 + chunk] = cnt;
}

// ---------------- pooled gate, stage 2: reduce partials, linear, softmax ----------------
__global__ __launch_bounds__(256) void k_pool2(const float* __restrict__ partial, const float* __restrict__ pcnt,
                                               const float* __restrict__ Wg, const float* __restrict__ bg,
                                               float* __restrict__ gate){
  int b = blockIdx.x, tid = threadIdx.x;
  __shared__ float red[256];
  __shared__ float hp[768];
  float a0 = 0.f, a1 = 0.f, a2 = 0.f;
#pragma unroll
  for (int c = 0; c < 8; c++){
    const float* p = partial + (size_t)(b * 8 + c) * D_;
    a0 += p[tid]; a1 += p[tid + 256]; a2 += p[tid + 512];
  }
  float denom = 0.f;
#pragma unroll
  for (int c = 0; c < 8; c++) denom += pcnt[b * 8 + c];
  float inv = 1.0f / fmaxf(denom, 1.0f);
  hp[tid] = a0 * inv; hp[tid + 256] = a1 * inv; hp[tid + 512] = a2 * inv;
  __syncthreads();
  float p0 = 0.f, p1 = 0.f;
  for (int d = tid; d < D_; d += 256){ p0 += hp[d] * Wg[d * 2]; p1 += hp[d] * Wg[d * 2 + 1]; }
  red[tid] = p0; __syncthreads();
  for (int o = 128; o > 0; o >>= 1){ if (tid < o) red[tid] += red[tid + o]; __syncthreads(); }
  float z0 = red[0]; __syncthreads();
  red[tid] = p1; __syncthreads();
  for (int o = 128; o > 0; o >>= 1){ if (tid < o) red[tid] += red[tid + o]; __syncthreads(); }
  float z1 = red[0];
  if (tid == 0){
    z0 = (z0 + bg[0]) * 0.5f; z1 = (z1 + bg[1]) * 0.5f;
    float m = fmaxf(z0, z1);
    float e0 = __expf(z0 - m), e1 = __expf(z1 - m);
    float ssum = e0 + e1;
    gate[b * 2] = e0 / ssum; gate[b * 2 + 1] = e1 / ssum;
  }
}

// ---------------- generic BT GEMM: C[z] = act(alpha*A[z]*B[z]^T + bias) ----------------
// EXP=1: C = exp(alpha*acc + bias) stored bf16, plus per-row partial sums into
// psum[blockIdx.x * BHS_ + z*S_ + m0 + rowlocal].
template<int BN, int OUTBF16, int RELU, int RESID, int EXP>
__global__ __launch_bounds__(256) void k_gemm_bt(
    const ushort_t* __restrict__ A, long sAb, long sAh, int lda,
    const ushort_t* __restrict__ Bm, long sBb, long sBh, int ldb,
    void* __restrict__ Cp, long sCb, long sCh, int ldc,
    const float* __restrict__ bias, long biasStride,
    const float* __restrict__ resid, float alpha, int K,
    float* __restrict__ psum)
{
  __shared__ ushort_t As[128 * 32];
  __shared__ ushort_t Bs[BN * 32];
  __shared__ float rsum[128];
  const int z = blockIdx.z;
  const int zb = z / H_, zh = z - zb * H_;
  const ushort_t* Ab = A + zb * sAb + zh * sAh;
  const ushort_t* Bb = Bm + zb * sBb + zh * sBh;
  const long coff = zb * sCb + zh * sCh;
  const int tid = threadIdx.x;
  const int m0 = blockIdx.y * 128, n0 = blockIdx.x * BN;
  const int wid = tid >> 6, lane = tid & 63;
  const int quad = lane >> 4, l16 = lane & 15;
  constexpr int MI = (BN == 128) ? 4 : 2;
  const int wm = (BN == 128) ? (wid >> 1) : wid;
  const int wn = (BN == 128) ? (wid & 1) : 0;

  if (EXP){ if (tid < 128) rsum[tid] = 0.0f; }

  f32x4 acc[MI][4];
#pragma unroll
  for (int i = 0; i < MI; i++)
#pragma unroll
    for (int j = 0; j < 4; j++) acc[i][j] = (f32x4){0.f, 0.f, 0.f, 0.f};

  for (int k0 = 0; k0 < K; k0 += 32){
#pragma unroll
    for (int c = 0; c < 2; c++){
      int chunk = tid + c * 256;          // 512 chunks of 8 bf16 for A tile
      int row = chunk >> 2, off = (chunk & 3) * 8;
      *(float4*)(&As[row * 32 + off]) = *(const float4*)(Ab + (size_t)(m0 + row) * lda + k0 + off);
    }
#pragma unroll
    for (int c = 0; c < (BN * 4) / 256; c++){
      int chunk = tid + c * 256;
      int row = chunk >> 2, off = (chunk & 3) * 8;
      *(float4*)(&Bs[row * 32 + off]) = *(const float4*)(Bb + (size_t)(n0 + row) * ldb + k0 + off);
    }
    __syncthreads();
    bf16x8 af[MI], bfv[4];
#pragma unroll
    for (int mi = 0; mi < MI; mi++)
      af[mi] = *(const bf16x8*)(&As[(wm * (MI * 16) + mi * 16 + l16) * 32 + quad * 8]);
#pragma unroll
    for (int ni = 0; ni < 4; ni++)
      bfv[ni] = *(const bf16x8*)(&Bs[(wn * 64 + ni * 16 + l16) * 32 + quad * 8]);
#pragma unroll
    for (int mi = 0; mi < MI; mi++)
#pragma unroll
      for (int ni = 0; ni < 4; ni++)
        acc[mi][ni] = __builtin_amdgcn_mfma_f32_16x16x32_bf16(af[mi], bfv[ni], acc[mi][ni], 0, 0, 0);
    __syncthreads();
  }

  const float* bv = bias ? (bias + zb * biasStride) : nullptr;
  if (EXP){
#pragma unroll
    for (int mi = 0; mi < MI; mi++){
      float rowacc[4] = {0.f, 0.f, 0.f, 0.f};
#pragma unroll
      for (int ni = 0; ni < 4; ni++){
        int col = n0 + wn * 64 + ni * 16 + l16;
        float bcol = bv[col];
#pragma unroll
        for (int r = 0; r < 4; r++){
          int row = m0 + wm * (MI * 16) + mi * 16 + quad * 4 + r;
          float v = __expf(acc[mi][ni][r] * alpha + bcol);
          ((ushort_t*)Cp)[coff + (long)row * ldc + col] = f2bf(v);
          rowacc[r] += v;
        }
      }
#pragma unroll
      for (int o = 1; o < 16; o <<= 1){
#pragma unroll
        for (int r = 0; r < 4; r++) rowacc[r] += __shfl_xor(rowacc[r], o);
      }
      if (l16 == 0){
#pragma unroll
        for (int r = 0; r < 4; r++)
          atomicAdd(&rsum[wm * (MI * 16) + mi * 16 + quad * 4 + r], rowacc[r]);
      }
    }
    __syncthreads();
    if (tid < 128)
      psum[(size_t)blockIdx.x * BHS_ + (size_t)z * S_ + m0 + tid] = rsum[tid];
    return;
  }

#pragma unroll
  for (int mi = 0; mi < MI; mi++){
#pragma unroll
    for (int ni = 0; ni < 4; ni++){
      int col = n0 + wn * 64 + ni * 16 + l16;
      float bcol = bv ? bv[col] : 0.0f;
#pragma unroll
      for (int r = 0; r < 4; r++){
        int row = m0 + wm * (MI * 16) + mi * 16 + quad * 4 + r;
        float v = acc[mi][ni][r] * alpha + bcol;
        if (RELU) v = fmaxf(v, 0.0f);
        if (RESID) v += resid[(size_t)row * ldc + col];
        long idx = coff + (long)row * ldc + col;
        if (OUTBF16) ((ushort_t*)Cp)[idx] = f2bf(v);
        else         ((float*)Cp)[idx] = v;
      }
    }
  }
}

// ---------------- scale = g0 / rowsum ----------------
__global__ __launch_bounds__(256) void k_scale(const float* __restrict__ psum,
                                               const float* __restrict__ gate,
                                               float* __restrict__ scl){
  int i = blockIdx.x * 256 + threadIdx.x;
  float l = psum[i] + psum[BHS_ + i] + psum[2 * BHS_ + i] + psum[3 * BHS_ + i];
  int b = i / (H_ * S_);
  scl[i] = gate[b * 2] / l;
}

// ---------------- fused PV: ctx = scl[row]*(E·V) + g1[b]*(prior·V) ----------------
__global__ __launch_bounds__(256) void k_pv_mix(
    const ushort_t* __restrict__ E, const ushort_t* __restrict__ priorb,
    const ushort_t* __restrict__ vt, ushort_t* __restrict__ ctx,
    const float* __restrict__ scl, const float* __restrict__ gate)
{
  __shared__ ushort_t As1[128 * 32];
  __shared__ ushort_t As2[128 * 32];
  __shared__ ushort_t Bs[64 * 32];
  const int z = blockIdx.z;
  const int b = z / H_, h = z - b * H_;
  const ushort_t* Ab1 = E + (size_t)z * S_ * S_;
  const ushort_t* Ab2 = priorb + (size_t)b * S_ * S_;
  const ushort_t* Bb = vt + (size_t)z * DH_ * S_;
  const int tid = threadIdx.x;
  const int m0 = blockIdx.y * 128;
  const int wid = tid >> 6, lane = tid & 63;
  const int quad = lane >> 4, l16 = lane & 15;
  const int wm = wid;

  f32x4 acc1[2][4], acc2[2][4];
#pragma unroll
  for (int i = 0; i < 2; i++)
#pragma unroll
    for (int j = 0; j < 4; j++){ acc1[i][j] = (f32x4){0.f,0.f,0.f,0.f}; acc2[i][j] = (f32x4){0.f,0.f,0.f,0.f}; }

  for (int k0 = 0; k0 < S_; k0 += 32){
#pragma unroll
    for (int c = 0; c < 2; c++){
      int chunk = tid + c * 256;
      int row = chunk >> 2, off = (chunk & 3) * 8;
      *(float4*)(&As1[row * 32 + off]) = *(const float4*)(Ab1 + (size_t)(m0 + row) * S_ + k0 + off);
      *(float4*)(&As2[row * 32 + off]) = *(const float4*)(Ab2 + (size_t)(m0 + row) * S_ + k0 + off);
    }
    {
      int row = tid >> 2, off = (tid & 3) * 8;
      *(float4*)(&Bs[row * 32 + off]) = *(const float4*)(Bb + (size_t)row * S_ + k0 + off);
    }
    __syncthreads();
    bf16x8 af1[2], af2[2], bfv[4];
#pragma unroll
    for (int mi = 0; mi < 2; mi++){
      af1[mi] = *(const bf16x8*)(&As1[(wm * 32 + mi * 16 + l16) * 32 + quad * 8]);
      af2[mi] = *(const bf16x8*)(&As2[(wm * 32 + mi * 16 + l16) * 32 + quad * 8]);
    }
#pragma unroll
    for (int ni = 0; ni < 4; ni++)
      bfv[ni] = *(const bf16x8*)(&Bs[(ni * 16 + l16) * 32 + quad * 8]);
#pragma unroll
    for (int mi = 0; mi < 2; mi++)
#pragma unroll
      for (int ni = 0; ni < 4; ni++){
        acc1[mi][ni] = __builtin_amdgcn_mfma_f32_16x16x32_bf16(af1[mi], bfv[ni], acc1[mi][ni], 0, 0, 0);
        acc2[mi][ni] = __builtin_amdgcn_mfma_f32_16x16x32_bf16(af2[mi], bfv[ni], acc2[mi][ni], 0, 0, 0);
      }
    __syncthreads();
  }

  float g1v = gate[b * 2 + 1];
#pragma unroll
  for (int mi = 0; mi < 2; mi++){
    float sc[4];
#pragma unroll
    for (int r = 0; r < 4; r++){
      int row_s = m0 + wm * 32 + mi * 16 + quad * 4 + r;
      sc[r] = scl[(size_t)z * S_ + row_s];
    }
#pragma unroll
    for (int ni = 0; ni < 4; ni++){
      int col = ni * 16 + l16;
#pragma unroll
      for (int r = 0; r < 4; r++){
        int row_s = m0 + wm * 32 + mi * 16 + quad * 4 + r;
        float v = acc1[mi][ni][r] * sc[r] + acc2[mi][ni][r] * g1v;
        ctx[((size_t)b * S_ + row_s) * D_ + h * DH_ + col] = f2bf(v);
      }
    }
  }
}

// ---------------- per-head V transpose: vt[b,h,d,s] = v[b,s,h*64+d] ----------------
__global__ __launch_bounds__(256) void k_vtrans(const ushort_t* __restrict__ v, ushort_t* __restrict__ vt){
  __shared__ ushort_t t[64][66];
  int st = blockIdx.x * 64; int z = blockIdx.y;
  int b = z / H_, h = z - b * H_;
  int tid = threadIdx.x;
  const ushort_t* src = v + (size_t)b * S_ * D_ + (size_t)st * D_ + h * DH_;
#pragma unroll
  for (int rep = 0; rep < 8; rep++){
    int idx = rep * 256 + tid;
    int i = idx >> 5, u = idx & 31;
    unsigned int val = *(const unsigned int*)(src + (size_t)i * D_ + u * 2);
    *(unsigned int*)(&t[i][u * 2]) = val;
  }
  __syncthreads();
  ushort_t* dst = vt + (size_t)z * DH_ * S_ + st;
#pragma unroll
  for (int rep = 0; rep < 8; rep++){
    int idx = rep * 256 + tid;
    int d = idx >> 5, u2 = idx & 31;
    unsigned int val = (unsigned int)t[u2 * 2][d] | ((unsigned int)t[u2 * 2 + 1][d] << 16);
    *(unsigned int*)(dst + (size_t)d * S_ + u2 * 2) = val;
  }
}

// ---------------- in-place LayerNorm over D=768 ----------------
__global__ __launch_bounds__(256) void k_ln(float* __restrict__ out, const float* __restrict__ gamma,
                                            const float* __restrict__ beta){
  __shared__ float red[256];
  int row = blockIdx.x, tid = threadIdx.x;
  float* p = out + (size_t)row * D_;
  float x0 = p[tid], x1 = p[tid + 256], x2 = p[tid + 512];
  red[tid] = x0 + x1 + x2; __syncthreads();
  for (int o = 128; o > 0; o >>= 1){ if (tid < o) red[tid] += red[tid + o]; __syncthreads(); }
  float mu = red[0] * (1.0f / 768.0f);
  __syncthreads();
  float d0 = x0 - mu, d1 = x1 - mu, d2 = x2 - mu;
  red[tid] = d0 * d0 + d1 * d1 + d2 * d2; __syncthreads();
  for (int o = 128; o > 0; o >>= 1){ if (tid < o) red[tid] += red[tid + o]; __syncthreads(); }
  float rs = rsqrtf(red[0] * (1.0f / 768.0f) + 1e-5f);
  p[tid]       = d0 * rs * gamma[tid]       + beta[tid];
  p[tid + 256] = d1 * rs * gamma[tid + 256] + beta[tid + 256];
  p[tid + 512] = d2 * rs * gamma[tid + 512] + beta[tid + 512];
}

extern "C" void kernel_launch(void* const* d_in, const int* in_sizes, int n_in,
                              void* d_out, int out_size, void* d_ws, size_t ws_size,
                              hipStream_t stream){
  const float* hs    = (const float*)d_in[0];
  const float* mask  = (const float*)d_in[1];
  const float* prior = (const float*)d_in[2];
  const float* Wq = (const float*)d_in[3];  const float* bq = (const float*)d_in[4];
  const float* Wk = (const float*)d_in[5];  const float* bk = (const float*)d_in[6];
  const float* Wv = (const float*)d_in[7];  const float* bv = (const float*)d_in[8];
  const float* Wg = (const float*)d_in[9];  const float* bg = (const float*)d_in[10];
  const float* Wo = (const float*)d_in[11]; const float* bo = (const float*)d_in[12];
  const float* gamma = (const float*)d_in[13]; const float* beta = (const float*)d_in[14];
  float* out = (float*)d_out;

  size_t off = 0;
  auto alloc = [&](size_t bytes) -> char* {
    char* p = (char*)d_ws + off;
    off += (bytes + 255) & ~(size_t)255;
    return p;
  };
  const size_t HSD = (size_t)NB_ * S_ * D_;          // 6.29M elems
  ushort_t* hsb    = (ushort_t*)alloc(HSD * 2);
  ushort_t* qb     = (ushort_t*)alloc(HSD * 2);
  ushort_t* kb     = (ushort_t*)alloc(HSD * 2);
  ushort_t* vb     = (ushort_t*)alloc(HSD * 2);
  ushort_t* vtb    = (ushort_t*)alloc(HSD * 2);
  ushort_t* wt     = (ushort_t*)alloc((size_t)4 * D_ * D_ * 2);
  ushort_t* eb     = (ushort_t*)alloc((size_t)NB_ * H_ * S_ * S_ * 2);
  ushort_t* priorb = (ushort_t*)alloc((size_t)NB_ * S_ * S_ * 2);
  ushort_t* ctx    = (ushort_t*)alloc(HSD * 2);
  float*    gate   = (float*)alloc(256);
  float*    partial= (float*)alloc((size_t)NB_ * 8 * D_ * 4);
  float*    pcnt   = (float*)alloc((size_t)NB_ * 8 * 4);
  float*    psum   = (float*)alloc((size_t)4 * BHS_ * 4);
  float*    scl    = (float*)alloc((size_t)BHS_ * 4);

  // 1. converts
  k_f32_to_bf16<<<dim3((int)(HSD / 4 / 256)), 256, 0, stream>>>(hs, hsb, (int)(HSD / 4));
  k_f32_to_bf16<<<dim3((NB_ * S_ * S_ / 4) / 256), 256, 0, stream>>>(prior, priorb, NB_ * S_ * S_ / 4);
  k_wtrans<<<dim3(24, 24, 4), 256, 0, stream>>>(Wq, Wk, Wv, Wo, wt);
  // 2. gate (two-stage parallel pooling)
  k_pool1<<<dim3(8, NB_), 256, 0, stream>>>(hs, mask, partial, pcnt);
  k_pool2<<<dim3(NB_), 256, 0, stream>>>(partial, pcnt, Wg, bg, gate);
  // 3. QKV projections (bf16 out)
  k_gemm_bt<128, 1, 0, 0, 0><<<dim3(6, 64, 1), 256, 0, stream>>>(
      hsb, 0, 0, D_, wt + 0 * (size_t)D_ * D_, 0, 0, D_, qb, 0, 0, D_, bq, 0, nullptr, 1.0f, D_, nullptr);
  k_gemm_bt<128, 1, 0, 0, 0><<<dim3(6, 64, 1), 256, 0, stream>>>(
      hsb, 0, 0, D_, wt + 1 * (size_t)D_ * D_, 0, 0, D_, kb, 0, 0, D_, bk, 0, nullptr, 1.0f, D_, nullptr);
  k_gemm_bt<128, 1, 0, 0, 0><<<dim3(6, 64, 1), 256, 0, stream>>>(
      hsb, 0, 0, D_, wt + 2 * (size_t)D_ * D_, 0, 0, D_, vb, 0, 0, D_, bv, 0, nullptr, 1.0f, D_, nullptr);
  // 4. E = exp(0.125*Q·K^T + mask), partial row sums (batched over B*H)
  k_gemm_bt<128, 1, 0, 0, 1><<<dim3(4, 4, NB_ * H_), 256, 0, stream>>>(
      qb, (long)S_ * D_, 64, D_, kb, (long)S_ * D_, 64, D_,
      eb, (long)H_ * S_ * S_, (long)S_ * S_, S_, mask, S_, nullptr, 0.125f, DH_, psum);
  // 5. scale = g0/l
  k_scale<<<dim3(BHS_ / 256), 256, 0, stream>>>(psum, gate, scl);
  // 6. V transpose per head
  k_vtrans<<<dim3(S_ / 64, NB_ * H_), 256, 0, stream>>>(vb, vtb);
  // 7. ctx = scl*(E·V) + g1*(prior·V)   (batched, bf16 out into [B,S,D] head slices)
  k_pv_mix<<<dim3(1, 4, NB_ * H_), 256, 0, stream>>>(eb, priorb, vtb, ctx, scl, gate);
  // 8. out = relu(ctx·Wo + bo) + hs  (fp32 into d_out)
  k_gemm_bt<128, 0, 1, 1, 0><<<dim3(6, 64, 1), 256, 0, stream>>>(
      ctx, 0, 0, D_, wt + 3 * (size_t)D_ * D_, 0, 0, D_, out, 0, 0, D_, bo, 0, hs, 1.0f, D_, nullptr);
  // 9. LayerNorm in place on d_out
  k_ln<<<dim3(NB_ * S_), 256, 0, stream>>>(out, gamma, beta);
}

// Round 4
// 324.647 us; speedup vs baseline: 1.5510x; 1.1172x over previous
//
#include <hip/hip_runtime.h>

#define NB_ 16   // batch
#define S_ 512
#define D_ 768
#define H_ 12
#define DH_ 64
#define QT_ 64   // flash q-tile
#define KT_ 128  // flash k-tile

typedef __attribute__((ext_vector_type(8))) short bf16x8;
typedef __attribute__((ext_vector_type(4))) float f32x4;
typedef unsigned short ushort_t;

__device__ __forceinline__ unsigned short f2bf(float f){
  unsigned int u = __float_as_uint(f);
  u += 0x7fffu + ((u >> 16) & 1u);   // round-to-nearest-even
  return (unsigned short)(u >> 16);
}
__device__ __forceinline__ float bf2f(unsigned short s){
  return __uint_as_float(((unsigned int)s) << 16);
}
// async global->LDS, 16B per lane. LDS side must be uniform-base + lane*16,
// which holds because chunk index is linear in tid within each wave.
__device__ __forceinline__ void gld16(const ushort_t* g, ushort_t* l){
  __builtin_amdgcn_global_load_lds((const __attribute__((address_space(1))) unsigned int*)g,
                                   (__attribute__((address_space(3))) unsigned int*)l, 16, 0, 0);
}

// ---------------- fp32 -> bf16 bulk convert ----------------
__global__ __launch_bounds__(256) void k_f32_to_bf16(const float* __restrict__ in,
                                                     ushort_t* __restrict__ out, int n4){
  int i = blockIdx.x * 256 + threadIdx.x;
  if (i < n4){
    float4 f = ((const float4*)in)[i];
    unsigned int lo = (unsigned int)f2bf(f.x) | ((unsigned int)f2bf(f.y) << 16);
    unsigned int hi = (unsigned int)f2bf(f.z) | ((unsigned int)f2bf(f.w) << 16);
    ((uint2*)out)[i] = make_uint2(lo, hi);
  }
}

// ---------------- weight transpose fp32[K][N] -> bf16[N][K] ----------------
__global__ __launch_bounds__(256) void k_wtrans(const float* __restrict__ W0, const float* __restrict__ W1,
                                                const float* __restrict__ W2, const float* __restrict__ W3,
                                                ushort_t* __restrict__ dst){
  const float* W = (blockIdx.z == 0) ? W0 : (blockIdx.z == 1) ? W1 : (blockIdx.z == 2) ? W2 : W3;
  ushort_t* o = dst + (size_t)blockIdx.z * D_ * D_;
  __shared__ float t[32][33];
  int j = threadIdx.x & 31, i0 = threadIdx.x >> 5;
  int kb = blockIdx.y * 32, nb = blockIdx.x * 32;
#pragma unroll
  for (int r = 0; r < 4; r++){
    int i = i0 + r * 8;
    t[i][j] = W[(size_t)(kb + i) * D_ + nb + j];
  }
  __syncthreads();
#pragma unroll
  for (int r = 0; r < 4; r++){
    int i = i0 + r * 8;
    o[(size_t)(nb + i) * D_ + kb + j] = f2bf(t[j][i]);
  }
}

// ---------------- concat bq|bk|bv -> [2304] ----------------
__global__ __launch_bounds__(256) void k_bias3(const float* __restrict__ b0, const float* __restrict__ b1,
                                               const float* __restrict__ b2, float* __restrict__ o){
  int i = blockIdx.x * 256 + threadIdx.x;
  if (i < 3 * D_){
    float v = (i < D_) ? b0[i] : (i < 2 * D_) ? b1[i - D_] : b2[i - 2 * D_];
    o[i] = v;
  }
}

// ---------------- pooled gate, stage 1 ----------------
__global__ __launch_bounds__(256) void k_pool1(const float* __restrict__ hs, const float* __restrict__ mask,
                                               float* __restrict__ partial, float* __restrict__ pcnt){
  int chunk = blockIdx.x, b = blockIdx.y, tid = threadIdx.x;
  const float* mrow = mask + b * S_ + chunk * 64;
  const float* base = hs + ((size_t)b * S_ + chunk * 64) * D_;
  float a0 = 0.f, a1 = 0.f, a2 = 0.f, cnt = 0.f;
#pragma unroll 4
  for (int s = 0; s < 64; s++){
    if (mrow[s] == 0.0f){
      const float* r = base + (size_t)s * D_;
      a0 += r[tid]; a1 += r[tid + 256]; a2 += r[tid + 512];
      cnt += 1.0f;
    }
  }
  float* o = partial + (size_t)(b * 8 + chunk) * D_;
  o[tid] = a0; o[tid + 256] = a1; o[tid + 512] = a2;
  if (tid == 0) pcnt[b * 8 + chunk] = cnt;
}

// ---------------- pooled gate, stage 2 ----------------
__global__ __launch_bounds__(256) void k_pool2(const float* __restrict__ partial, const float* __restrict__ pcnt,
                                               const float* __restrict__ Wg, const float* __restrict__ bg,
                                               float* __restrict__ gate){
  int b = blockIdx.x, tid = threadIdx.x;
  __shared__ float red[256];
  __shared__ float hp[768];
  float a0 = 0.f, a1 = 0.f, a2 = 0.f;
#pragma unroll
  for (int c = 0; c < 8; c++){
    const float* p = partial + (size_t)(b * 8 + c) * D_;
    a0 += p[tid]; a1 += p[tid + 256]; a2 += p[tid + 512];
  }
  float denom = 0.f;
#pragma unroll
  for (int c = 0; c < 8; c++) denom += pcnt[b * 8 + c];
  float inv = 1.0f / fmaxf(denom, 1.0f);
  hp[tid] = a0 * inv; hp[tid + 256] = a1 * inv; hp[tid + 512] = a2 * inv;
  __syncthreads();
  float p0 = 0.f, p1 = 0.f;
  for (int d = tid; d < D_; d += 256){ p0 += hp[d] * Wg[d * 2]; p1 += hp[d] * Wg[d * 2 + 1]; }
  red[tid] = p0; __syncthreads();
  for (int o = 128; o > 0; o >>= 1){ if (tid < o) red[tid] += red[tid + o]; __syncthreads(); }
  float z0 = red[0]; __syncthreads();
  red[tid] = p1; __syncthreads();
  for (int o = 128; o > 0; o >>= 1){ if (tid < o) red[tid] += red[tid + o]; __syncthreads(); }
  float z1 = red[0];
  if (tid == 0){
    z0 = (z0 + bg[0]) * 0.5f; z1 = (z1 + bg[1]) * 0.5f;
    float m = fmaxf(z0, z1);
    float e0 = __expf(z0 - m), e1 = __expf(z1 - m);
    float ssum = e0 + e1;
    gate[b * 2] = e0 / ssum; gate[b * 2 + 1] = e1 / ssum;
  }
}

// ---------------- BT GEMM (128x128 tile, global_load_lds staging) ----------------
// C[z] = act(alpha*A[z]*B[z]^T + bias [+ resid]); A:[M][K] lda, B:[N][K] ldb.
template<int OUTBF16, int RELU, int RESID>
__global__ __launch_bounds__(256) void k_gemm_bt(
    const ushort_t* __restrict__ A, long sA, int lda,
    const ushort_t* __restrict__ Bm, long sB, int ldb,
    void* __restrict__ Cp, long sC, int ldc,
    const float* __restrict__ bias,
    const float* __restrict__ resid, float alpha, int K)
{
  __shared__ ushort_t As[128 * 32];
  __shared__ ushort_t Bs[128 * 32];
  const int z = blockIdx.z;
  const ushort_t* Ab = A + (size_t)z * sA;
  const ushort_t* Bb = Bm + (size_t)z * sB;
  const long coff = (long)z * sC;
  const int tid = threadIdx.x;
  const int m0 = blockIdx.y * 128, n0 = blockIdx.x * 128;
  const int wid = tid >> 6, lane = tid & 63;
  const int quad = lane >> 4, l16 = lane & 15;
  const int wm = wid >> 1, wn = wid & 1;

  f32x4 acc[4][4];
#pragma unroll
  for (int i = 0; i < 4; i++)
#pragma unroll
    for (int j = 0; j < 4; j++) acc[i][j] = (f32x4){0.f, 0.f, 0.f, 0.f};

  for (int k0 = 0; k0 < K; k0 += 32){
#pragma unroll
    for (int c = 0; c < 2; c++){
      int chunk = tid + c * 256;
      int row = chunk >> 2, off = (chunk & 3) * 8;
      gld16(Ab + (size_t)(m0 + row) * lda + k0 + off, &As[chunk * 8]);
    }
#pragma unroll
    for (int c = 0; c < 2; c++){
      int chunk = tid + c * 256;
      int row = chunk >> 2, off = (chunk & 3) * 8;
      gld16(Bb + (size_t)(n0 + row) * ldb + k0 + off, &Bs[chunk * 8]);
    }
    __syncthreads();
    bf16x8 af[4], bfv[4];
#pragma unroll
    for (int mi = 0; mi < 4; mi++)
      af[mi] = *(const bf16x8*)(&As[(wm * 64 + mi * 16 + l16) * 32 + quad * 8]);
#pragma unroll
    for (int ni = 0; ni < 4; ni++)
      bfv[ni] = *(const bf16x8*)(&Bs[(wn * 64 + ni * 16 + l16) * 32 + quad * 8]);
#pragma unroll
    for (int mi = 0; mi < 4; mi++)
#pragma unroll
      for (int ni = 0; ni < 4; ni++)
        acc[mi][ni] = __builtin_amdgcn_mfma_f32_16x16x32_bf16(af[mi], bfv[ni], acc[mi][ni], 0, 0, 0);
    __syncthreads();
  }

#pragma unroll
  for (int mi = 0; mi < 4; mi++){
#pragma unroll
    for (int ni = 0; ni < 4; ni++){
      int col = n0 + wn * 64 + ni * 16 + l16;
      float bcol = bias ? bias[col] : 0.0f;
#pragma unroll
      for (int r = 0; r < 4; r++){
        int row = m0 + wm * 64 + mi * 16 + quad * 4 + r;
        float v = acc[mi][ni][r] * alpha + bcol;
        if (RELU) v = fmaxf(v, 0.0f);
        if (RESID) v += resid[(size_t)row * ldc + col];
        long idx = coff + (long)row * ldc + col;
        if (OUTBF16) ((ushort_t*)Cp)[idx] = f2bf(v);
        else         ((float*)Cp)[idx] = v;
      }
    }
  }
}

// ---------------- per-head V transpose: vt[z][dh][t] = v[b,t,(voff)+h*64+dh] ----------------
__global__ __launch_bounds__(256) void k_vtrans(const ushort_t* __restrict__ v, int ldv,
                                                ushort_t* __restrict__ vt){
  __shared__ ushort_t t[64][66];
  int st = blockIdx.x * 64; int z = blockIdx.y;
  int b = z / H_, h = z - b * H_;
  int tid = threadIdx.x;
  const ushort_t* src = v + ((size_t)b * S_ + st) * ldv + h * DH_;
#pragma unroll
  for (int rep = 0; rep < 8; rep++){
    int idx = rep * 256 + tid;
    int i = idx >> 5, u = idx & 31;
    unsigned int val = *(const unsigned int*)(src + (size_t)i * ldv + u * 2);
    *(unsigned int*)(&t[i][u * 2]) = val;
  }
  __syncthreads();
  ushort_t* dst = vt + (size_t)z * DH_ * S_ + st;
#pragma unroll
  for (int rep = 0; rep < 8; rep++){
    int idx = rep * 256 + tid;
    int d = idx >> 5, u2 = idx & 31;
    unsigned int val = (unsigned int)t[u2 * 2][d] | ((unsigned int)t[u2 * 2 + 1][d] << 16);
    *(unsigned int*)(dst + (size_t)d * S_ + u2 * 2) = val;
  }
}

// ---------------- fused flash attention with prior blend ----------------
// ctx[b,q,h*64+dh] = (g0/l_q) * sum_t exp(0.125*q.k + mask_t) * V[t,dh] + g1 * priorctx[b,q,h*64+dh]
__global__ __launch_bounds__(256) void k_flash(
    const ushort_t* __restrict__ qkv,      // [B*S][2304]; q at col 0, k at col 768
    const ushort_t* __restrict__ vt,       // [B*H][64][512]
    const ushort_t* __restrict__ priorctx, // [B*S][768] bf16
    const float* __restrict__ mask,        // [B][S]
    const float* __restrict__ gate,        // [B][2]
    ushort_t* __restrict__ ctx)            // [B*S][768]
{
  __shared__ ushort_t Qs[QT_ * 72];    // [q][dh], pad to 72
  __shared__ ushort_t Ks[KT_ * 72];    // [t][dh]
  __shared__ ushort_t Vs[DH_ * 136];   // [dh][t], pad to 136
  __shared__ ushort_t Ps[QT_ * 136];   // [q][t]
  __shared__ float rs[QT_];
  const int z = blockIdx.z, b = z / H_, h = z - b * H_;
  const int q0 = blockIdx.x * QT_;
  const int tid = threadIdx.x;
  const int wid = tid >> 6, lane = tid & 63, quad = lane >> 4, l16 = lane & 15;

  // stage Q tile (64 x 64)
#pragma unroll
  for (int i = 0; i < 2; i++){
    int c = tid + i * 256;
    int row = c >> 3, off = (c & 7) * 8;
    *(float4*)(&Qs[row * 72 + off]) =
      *(const float4*)(qkv + ((size_t)(b * S_ + q0 + row)) * 2304 + h * DH_ + off);
  }
  if (tid < QT_) rs[tid] = 0.f;

  f32x4 accv[4];
#pragma unroll
  for (int ni = 0; ni < 4; ni++) accv[ni] = (f32x4){0.f, 0.f, 0.f, 0.f};

  for (int t0 = 0; t0 < S_; t0 += KT_){
    // stage K tile (128 x 64) and V^T tile (64 x 128)
#pragma unroll
    for (int i = 0; i < 4; i++){
      int c = tid + i * 256;
      int row = c >> 3, off = (c & 7) * 8;
      *(float4*)(&Ks[row * 72 + off]) =
        *(const float4*)(qkv + ((size_t)(b * S_ + t0 + row)) * 2304 + D_ + h * DH_ + off);
    }
#pragma unroll
    for (int i = 0; i < 4; i++){
      int c = tid + i * 256;
      int row = c >> 4, off = (c & 15) * 8;
      *(float4*)(&Vs[row * 136 + off]) =
        *(const float4*)(vt + (size_t)z * (DH_ * S_) + (size_t)row * S_ + t0 + off);
    }
    __syncthreads();

    // S^T = K·Q^T : A = K tokens (m, 128), B = Q rows (n, 64), k-dim = dh (64)
    f32x4 accs[2][4];
#pragma unroll
    for (int mi = 0; mi < 2; mi++)
#pragma unroll
      for (int ni = 0; ni < 4; ni++) accs[mi][ni] = (f32x4){0.f, 0.f, 0.f, 0.f};
    bf16x8 ak[2][2], bq[4][2];
#pragma unroll
    for (int mi = 0; mi < 2; mi++)
#pragma unroll
      for (int ks = 0; ks < 2; ks++)
        ak[mi][ks] = *(const bf16x8*)(&Ks[(wid * 32 + mi * 16 + l16) * 72 + ks * 32 + quad * 8]);
#pragma unroll
    for (int ni = 0; ni < 4; ni++)
#pragma unroll
      for (int ks = 0; ks < 2; ks++)
        bq[ni][ks] = *(const bf16x8*)(&Qs[(ni * 16 + l16) * 72 + ks * 32 + quad * 8]);
#pragma unroll
    for (int mi = 0; mi < 2; mi++)
#pragma unroll
      for (int ni = 0; ni < 4; ni++){
        accs[mi][ni] = __builtin_amdgcn_mfma_f32_16x16x32_bf16(ak[mi][0], bq[ni][0], accs[mi][ni], 0, 0, 0);
        accs[mi][ni] = __builtin_amdgcn_mfma_f32_16x16x32_bf16(ak[mi][1], bq[ni][1], accs[mi][ni], 0, 0, 0);
      }

    // exp + pack into Ps[q][t] (lane holds 4 contiguous t for fixed q) + row sums
    float mv[2][4];
#pragma unroll
    for (int mi = 0; mi < 2; mi++)
#pragma unroll
      for (int r = 0; r < 4; r++)
        mv[mi][r] = mask[b * S_ + t0 + wid * 32 + mi * 16 + quad * 4 + r];
    float rowpart[4] = {0.f, 0.f, 0.f, 0.f};
#pragma unroll
    for (int mi = 0; mi < 2; mi++){
#pragma unroll
      for (int ni = 0; ni < 4; ni++){
        float e0 = __expf(accs[mi][ni][0] * 0.125f + mv[mi][0]);
        float e1 = __expf(accs[mi][ni][1] * 0.125f + mv[mi][1]);
        float e2 = __expf(accs[mi][ni][2] * 0.125f + mv[mi][2]);
        float e3 = __expf(accs[mi][ni][3] * 0.125f + mv[mi][3]);
        rowpart[ni] += (e0 + e1) + (e2 + e3);
        uint2 pk;
        pk.x = (unsigned int)f2bf(e0) | ((unsigned int)f2bf(e1) << 16);
        pk.y = (unsigned int)f2bf(e2) | ((unsigned int)f2bf(e3) << 16);
        *(uint2*)(&Ps[(ni * 16 + l16) * 136 + wid * 32 + mi * 16 + quad * 4]) = pk;
      }
    }
#pragma unroll
    for (int ni = 0; ni < 4; ni++){
      rowpart[ni] += __shfl_xor(rowpart[ni], 16);
      rowpart[ni] += __shfl_xor(rowpart[ni], 32);
    }
    if (lane < 16){
#pragma unroll
      for (int ni = 0; ni < 4; ni++) atomicAdd(&rs[ni * 16 + l16], rowpart[ni]);
    }
    __syncthreads();

    // PV: A = Ps (m = q, this wave's 16 rows), B = Vs (n = dh), k = t (128)
#pragma unroll
    for (int ks = 0; ks < 4; ks++){
      bf16x8 ap = *(const bf16x8*)(&Ps[(wid * 16 + l16) * 136 + ks * 32 + quad * 8]);
#pragma unroll
      for (int ni = 0; ni < 4; ni++){
        bf16x8 bv8 = *(const bf16x8*)(&Vs[(ni * 16 + l16) * 136 + ks * 32 + quad * 8]);
        accv[ni] = __builtin_amdgcn_mfma_f32_16x16x32_bf16(ap, bv8, accv[ni], 0, 0, 0);
      }
    }
    __syncthreads();
  }

  const float g0 = gate[b * 2], g1 = gate[b * 2 + 1];
#pragma unroll
  for (int ni = 0; ni < 4; ni++){
#pragma unroll
    for (int r = 0; r < 4; r++){
      int q = wid * 16 + quad * 4 + r;
      int dh = ni * 16 + l16;
      float scl = g0 / rs[q];
      size_t idx = ((size_t)(b * S_ + q0 + q)) * D_ + h * DH_ + dh;
      float v = accv[ni][r] * scl + g1 * bf2f(priorctx[idx]);
      ctx[idx] = f2bf(v);
    }
  }
}

// ---------------- in-place LayerNorm over D=768 ----------------
__global__ __launch_bounds__(256) void k_ln(float* __restrict__ out, const float* __restrict__ gamma,
                                            const float* __restrict__ beta){
  __shared__ float red[256];
  int row = blockIdx.x, tid = threadIdx.x;
  float* p = out + (size_t)row * D_;
  float x0 = p[tid], x1 = p[tid + 256], x2 = p[tid + 512];
  red[tid] = x0 + x1 + x2; __syncthreads();
  for (int o = 128; o > 0; o >>= 1){ if (tid < o) red[tid] += red[tid + o]; __syncthreads(); }
  float mu = red[0] * (1.0f / 768.0f);
  __syncthreads();
  float d0 = x0 - mu, d1 = x1 - mu, d2 = x2 - mu;
  red[tid] = d0 * d0 + d1 * d1 + d2 * d2; __syncthreads();
  for (int o = 128; o > 0; o >>= 1){ if (tid < o) red[tid] += red[tid + o]; __syncthreads(); }
  float rsv = rsqrtf(red[0] * (1.0f / 768.0f) + 1e-5f);
  p[tid]       = d0 * rsv * gamma[tid]       + beta[tid];
  p[tid + 256] = d1 * rsv * gamma[tid + 256] + beta[tid + 256];
  p[tid + 512] = d2 * rsv * gamma[tid + 512] + beta[tid + 512];
}

extern "C" void kernel_launch(void* const* d_in, const int* in_sizes, int n_in,
                              void* d_out, int out_size, void* d_ws, size_t ws_size,
                              hipStream_t stream){
  const float* hs    = (const float*)d_in[0];
  const float* mask  = (const float*)d_in[1];
  const float* prior = (const float*)d_in[2];
  const float* Wq = (const float*)d_in[3];  const float* bq = (const float*)d_in[4];
  const float* Wk = (const float*)d_in[5];  const float* bk = (const float*)d_in[6];
  const float* Wv = (const float*)d_in[7];  const float* bv = (const float*)d_in[8];
  const float* Wg = (const float*)d_in[9];  const float* bg = (const float*)d_in[10];
  const float* Wo = (const float*)d_in[11]; const float* bo = (const float*)d_in[12];
  const float* gamma = (const float*)d_in[13]; const float* beta = (const float*)d_in[14];
  float* out = (float*)d_out;

  size_t off = 0;
  auto alloc = [&](size_t bytes) -> char* {
    char* p = (char*)d_ws + off;
    off += (bytes + 255) & ~(size_t)255;
    return p;
  };
  const size_t HSD = (size_t)NB_ * S_ * D_;            // 6.29M elems
  ushort_t* hsb     = (ushort_t*)alloc(HSD * 2);
  ushort_t* qkvb    = (ushort_t*)alloc(HSD * 3 * 2);   // [B*S][2304]
  ushort_t* vtb     = (ushort_t*)alloc(HSD * 2);       // [B*H][64][512]
  ushort_t* wt      = (ushort_t*)alloc((size_t)4 * D_ * D_ * 2);
  ushort_t* priorb  = (ushort_t*)alloc((size_t)NB_ * S_ * S_ * 2);
  ushort_t* priorctx= (ushort_t*)alloc(HSD * 2);
  ushort_t* ctx     = (ushort_t*)alloc(HSD * 2);
  float*    bqkv    = (float*)alloc((size_t)3 * D_ * 4);
  float*    gate    = (float*)alloc(256);
  float*    partial = (float*)alloc((size_t)NB_ * 8 * D_ * 4);
  float*    pcnt    = (float*)alloc((size_t)NB_ * 8 * 4);

  // 1. converts / packs
  k_f32_to_bf16<<<dim3((int)(HSD / 4 / 256)), 256, 0, stream>>>(hs, hsb, (int)(HSD / 4));
  k_f32_to_bf16<<<dim3((NB_ * S_ * S_ / 4) / 256), 256, 0, stream>>>(prior, priorb, NB_ * S_ * S_ / 4);
  k_wtrans<<<dim3(24, 24, 4), 256, 0, stream>>>(Wq, Wk, Wv, Wo, wt);
  k_bias3<<<dim3(9), 256, 0, stream>>>(bq, bk, bv, bqkv);
  // 2. gate
  k_pool1<<<dim3(8, NB_), 256, 0, stream>>>(hs, mask, partial, pcnt);
  k_pool2<<<dim3(NB_), 256, 0, stream>>>(partial, pcnt, Wg, bg, gate);
  // 3. fused QKV projection: [8192x768] x [2304x768]^T -> [8192][2304]
  k_gemm_bt<1, 0, 0><<<dim3(18, 64, 1), 256, 0, stream>>>(
      hsb, 0, D_, wt, 0, D_, qkvb, 0, 3 * D_, bqkv, nullptr, 1.0f, D_);
  // 4. V transpose per head (v at col 1536 of qkvb)
  k_vtrans<<<dim3(S_ / 64, NB_ * H_), 256, 0, stream>>>(qkvb + 2 * D_, 3 * D_, vtb);
  // 5. priorctx = prior @ V  (per batch: [512x512] x vt[b]^T([768x512]) -> [512][768])
  k_gemm_bt<1, 0, 0><<<dim3(6, 4, NB_), 256, 0, stream>>>(
      priorb, (long)S_ * S_, S_, vtb, (long)H_ * DH_ * S_, S_,
      priorctx, (long)S_ * D_, D_, nullptr, nullptr, 1.0f, S_);
  // 6. flash attention + prior blend -> ctx (bf16)
  k_flash<<<dim3(S_ / QT_, 1, NB_ * H_), 256, 0, stream>>>(
      qkvb, vtb, priorctx, mask, gate, ctx);
  // 7. out = relu(ctx·Wo + bo) + hs  (fp32 into d_out)
  k_gemm_bt<0, 1, 1><<<dim3(6, 64, 1), 256, 0, stream>>>(
      ctx, 0, D_, wt + 3 * (size_t)D_ * D_, 0, D_, out, 0, D_, bo, hs, 1.0f, D_);
  // 8. LayerNorm in place on d_out
  k_ln<<<dim3(NB_ * S_), 256, 0, stream>>>(out, gamma, beta);
}